// Round 18
// baseline (119.916 us; speedup 1.0000x reference)
//
#include <hip/hip_runtime.h>
#include <stdint.h>

// LIF -> 1x1conv(512->2048) -> BN -> LIF -> 1x1conv(2048->512) -> BN -> +x
// T=4 B=32 C=512 Ch=2048 HW=196.
// R18 = R11 (104.5us best) + gemm2 with B-ONLY double buffer (80KB LDS,
// keeps 2 blocks/CU) and counted vmcnt: B(k+1) awaited a FULL iteration
// after issue (real latency cover), A reloaded per tile from L2 (~250cy).

typedef float f32x4 __attribute__((ext_vector_type(4)));
typedef int i32x4 __attribute__((ext_vector_type(4)));

#define TPLANE 3211264u     // B*C*HW
#define NCOL   6272u        // B*HW
#define MFMA_I8 __builtin_amdgcn_mfma_i32_16x16x64_i8
#define VMW(n) asm volatile("s_waitcnt vmcnt(" #n ")" ::: "memory")
#define LGK0() asm volatile("s_waitcnt lgkmcnt(0)" ::: "memory")
#define RBAR() __builtin_amdgcn_s_barrier()

static __device__ __forceinline__ void async16(const void* g, void* l) {
  __builtin_amdgcn_global_load_lds((const __attribute__((address_space(1))) uint32_t*)g,
                                   (__attribute__((address_space(3))) uint32_t*)l, 16, 0, 0);
}

// ---------------------------------------------------------------------------
// prep1: W1 -> per-row i8 [2048][512]; quant scale folded into BN1 scale.
__global__ void prep1_kernel(const float* __restrict__ W1,
                             const float* __restrict__ g1, const float* __restrict__ b1,
                             const float* __restrict__ m1, const float* __restrict__ v1,
                             signed char* __restrict__ W1q,
                             float* __restrict__ scale1, float* __restrict__ bias1) {
  __shared__ float red[256];
  const uint32_t c = blockIdx.x, tid = threadIdx.x;   // 2048 blocks x 256 thr
  const float* row = W1 + (size_t)c * 512u;
  float v0 = row[tid], v1l = row[tid + 256u];
  float mx = fmaxf(fabsf(v0), fabsf(v1l));
  red[tid] = mx; __syncthreads();
  for (uint32_t s = 128u; s > 0u; s >>= 1) {
    if (tid < s) red[tid] = fmaxf(red[tid], red[tid + s]);
    __syncthreads();
  }
  const float rmax = red[0];
  const float inv = rmax > 0.f ? 127.f / rmax : 0.f;
  W1q[(size_t)c * 512u + tid]        = (signed char)__float2int_rn(v0 * inv);
  W1q[(size_t)c * 512u + tid + 256u] = (signed char)__float2int_rn(v1l * inv);
  if (tid == 0) {
    float bn = g1[c] / sqrtf(v1[c] + 1e-5f);
    scale1[c] = (rmax / 127.f) * bn;          // dequant folded
    bias1[c]  = b1[c] - m1[c] * bn;
  }
}

// ---------------------------------------------------------------------------
// prep2: W2 -> per-row i8 quant [512][2048]; quant scale folded into BN2.
__global__ void prep2_kernel(const float* __restrict__ W2,
                             const float* __restrict__ g2, const float* __restrict__ b2,
                             const float* __restrict__ m2, const float* __restrict__ v2,
                             signed char* __restrict__ W2q,
                             float* __restrict__ scale2, float* __restrict__ bias2) {
  __shared__ float red[256];
  const uint32_t c = blockIdx.x, tid = threadIdx.x;
  const float* row = W2 + (size_t)c * 2048u;
  float vals[8];
  float mx = 0.f;
  #pragma unroll
  for (int j = 0; j < 8; ++j) {
    vals[j] = row[tid + 256u * (uint32_t)j];
    mx = fmaxf(mx, fabsf(vals[j]));
  }
  red[tid] = mx; __syncthreads();
  for (uint32_t s = 128u; s > 0u; s >>= 1) {
    if (tid < s) red[tid] = fmaxf(red[tid], red[tid + s]);
    __syncthreads();
  }
  const float rmax = red[0];
  const float inv = rmax > 0.f ? 127.f / rmax : 0.f;
  #pragma unroll
  for (int j = 0; j < 8; ++j)
    W2q[(size_t)c * 2048u + tid + 256u * (uint32_t)j] =
        (signed char)__float2int_rn(vals[j] * inv);
  if (tid == 0) {
    float bn = g2[c] / sqrtf(v2[c] + 1e-5f);
    scale2[c] = (rmax / 127.f) * bn;
    bias2[c]  = b2[c] - m2[c] * bn;
  }
}

// ---------------------------------------------------------------------------
// LIF over input (bit-exact fp32), spikes i8 {0,1} in K-blocked layout:
// chunk = (cb16*4 + t)*NCOL + n; 16B chunk = 16 consecutive channels.
__global__ void lif1_kernel(const float* __restrict__ x, signed char* __restrict__ s1) {
  __shared__ __align__(16) uint16_t sl[64 * 66 * 4];   // [c:64][n:66 pad][t:4], value 0/1
  const uint32_t tid = threadIdx.x;
  const uint32_t c0 = blockIdx.x * 64u;
  const uint32_t n0 = blockIdx.y * 64u;
  #pragma unroll
  for (int j = 0; j < 16; ++j) {
    uint32_t idx = (uint32_t)j * 256u + tid;
    uint32_t cl = idx >> 6, nl = idx & 63u;
    uint32_t n = n0 + nl;
    uint32_t b = n / 196u, hw = n - b * 196u;
    const float* px = x + (size_t)(b * 512u + c0 + cl) * 196u + hw;
    float v = 0.f;
    uint16_t sp[4];
    #pragma unroll
    for (int t = 0; t < 4; ++t) {
      float xv = px[(size_t)t * TPLANE];
      v += (xv - v) * 0.5f;                // exact: *0.5 never rounds
      bool s = (v >= 1.0f);
      sp[t] = s ? (uint16_t)1u : (uint16_t)0u;
      v = s ? 0.f : v;
    }
    uint2 pk;
    pk.x = (uint32_t)sp[0] | ((uint32_t)sp[1] << 16);
    pk.y = (uint32_t)sp[2] | ((uint32_t)sp[3] << 16);
    *(uint2*)&sl[(cl * 66u + nl) * 4u] = pk;
  }
  __syncthreads();
  // consumer: pack 16 channels (bytes) per chunk at fixed (t, n)
  #pragma unroll
  for (int j = 0; j < 4; ++j) {
    uint32_t id = (uint32_t)j * 256u + tid;              // 1024 chunks
    uint32_t nl = id & 63u, t = (id >> 6) & 3u, cb = id >> 8;   // cb: 0..3
    uint32_t us[4];
    #pragma unroll
    for (int w = 0; w < 4; ++w) {
      uint32_t b0 = sl[((cb * 16u + (uint32_t)w * 4u + 0u) * 66u + nl) * 4u + t];
      uint32_t b1 = sl[((cb * 16u + (uint32_t)w * 4u + 1u) * 66u + nl) * 4u + t];
      uint32_t b2 = sl[((cb * 16u + (uint32_t)w * 4u + 2u) * 66u + nl) * 4u + t];
      uint32_t b3 = sl[((cb * 16u + (uint32_t)w * 4u + 3u) * 66u + nl) * 4u + t];
      us[w] = b0 | (b1 << 8) | (b2 << 16) | (b3 << 24);
    }
    uint32_t chunk = (((c0 >> 4) + cb) * 4u + t) * NCOL + n0 + nl;
    uint4 o4; o4.x = us[0]; o4.y = us[1]; o4.z = us[2]; o4.w = us[3];
    *(uint4*)(s1 + (size_t)chunk * 16u) = o4;
  }
}

// ---------------------------------------------------------------------------
// GEMM1 (i8, R11-proven): M=2048, K=512 (BK=128 i8, 4 K-tiles), N-strip
// 64n x 4t, 48KB LDS, 32 MFMA/wave/barrier-pair. Fused dequant+BN1 +
// in-register LIF2 scan -> s2 i8 spike bytes. XCD swizzle over 1568 blocks.
__launch_bounds__(512)
__global__ void gemm1_lif2_kernel(const signed char* __restrict__ W1q,
                                  const signed char* __restrict__ s1,
                                  const float* __restrict__ scale1,
                                  const float* __restrict__ bias1,
                                  signed char* __restrict__ s2) {
  __shared__ __align__(16) char lds[49152];
  char* ldsA = lds;               // 16KB: [i:128][q':8]*16B, q' = q ^ (i&7)
  char* ldsB = lds + 16384;       // 32KB: [kb:8][t:4][dn:64]*16B
  const uint32_t tid = threadIdx.x;
  const uint32_t wid = tid >> 6;
  const uint32_t lane = tid & 63u;
  const uint32_t il = lane & 15u, g = lane >> 4;
  const uint32_t wm = wid >> 2, wn = wid & 3u;
  const uint32_t bid = blockIdx.x;
  const uint32_t lid = (bid & 7u) * 196u + (bid >> 3);   // 1568 = 8*196
  const uint32_t m0 = (lid & 15u) * 128u;                // 16 M-blocks
  const uint32_t n0 = (lid >> 4) * 64u;                  // 98 N-blocks

  i32x4 acc[4][4];                // [fm][t]
  #pragma unroll
  for (int i = 0; i < 4; ++i)
    #pragma unroll
    for (int j = 0; j < 4; ++j) acc[i][j] = (i32x4){0, 0, 0, 0};

  for (int kt = 0; kt < 4; ++kt) {
    #pragma unroll
    for (uint32_t r = 0; r < 4; ++r) {     // B tile: 2048 16B chunks
      uint32_t cid = r * 512u + tid;
      uint32_t kb = cid >> 8, rem = cid & 255u;
      uint32_t tt = rem >> 6, dn = rem & 63u;
      const char* src = (const char*)s1
          + (size_t)((((uint32_t)kt * 8u + kb) * 4u + tt) * NCOL + n0 + dn) * 16u;
      async16(src, ldsB + (size_t)cid * 16u);
    }
    #pragma unroll
    for (uint32_t r = 0; r < 2; ++r) {     // A tile: 1024 16B chunks
      uint32_t cid = r * 512u + tid;
      uint32_t i = cid >> 3, q = cid & 7u;
      const char* src = (const char*)W1q + (size_t)(m0 + i) * 512u
                        + (size_t)((uint32_t)kt * 128u) + (size_t)((q ^ (i & 7u)) * 16u);
      async16(src, ldsA + (size_t)cid * 16u);
    }
    __syncthreads();
    #pragma unroll
    for (int ks = 0; ks < 2; ++ks) {       // two K=64 halves of BK=128
      i32x4 af[4], bfr0, bfr1;
      #pragma unroll
      for (int fm = 0; fm < 4; ++fm) {
        uint32_t i = wm * 64u + (uint32_t)fm * 16u + il;
        uint32_t q = (uint32_t)ks * 4u + g;
        af[fm] = *(const i32x4*)(ldsA + (i * 8u + (q ^ (i & 7u))) * 16u);
      }
      #pragma unroll
      for (int th = 0; th < 2; ++th) {
        uint32_t chb = ((((uint32_t)ks * 4u + g) * 4u + (uint32_t)th * 2u) * 64u
                        + wn * 16u + il) * 16u;
        bfr0 = *(const i32x4*)(ldsB + chb);
        bfr1 = *(const i32x4*)(ldsB + chb + 1024u);
        #pragma unroll
        for (int fm = 0; fm < 4; ++fm) {
          acc[fm][th*2]   = MFMA_I8(af[fm], bfr0, acc[fm][th*2], 0, 0, 0);
          acc[fm][th*2+1] = MFMA_I8(af[fm], bfr1, acc[fm][th*2+1], 0, 0, 0);
        }
      }
    }
    __syncthreads();
  }

  // epilogue: dequant+BN1 (folded) + in-register LIF2 scan -> s2 i8 bytes
  const uint32_t n = n0 + wn * 16u + il;
  #pragma unroll
  for (int fm = 0; fm < 4; ++fm) {
    const uint32_t ch0 = m0 + wm * 64u + (uint32_t)fm * 16u + 4u * g;
    f32x4 sc = *(const f32x4*)&scale1[ch0];
    f32x4 bi = *(const f32x4*)&bias1[ch0];
    float v0 = 0.f, v1 = 0.f, v2 = 0.f, v3 = 0.f;
    #pragma unroll
    for (int t = 0; t < 4; ++t) {
      float h0 = (float)acc[fm][t][0] * sc[0] + bi[0];
      float h1 = (float)acc[fm][t][1] * sc[1] + bi[1];
      float h2 = (float)acc[fm][t][2] * sc[2] + bi[2];
      float h3 = (float)acc[fm][t][3] * sc[3] + bi[3];
      v0 += (h0 - v0) * 0.5f; bool s0 = (v0 >= 1.0f); v0 = s0 ? 0.f : v0;
      v1 += (h1 - v1) * 0.5f; bool s1v = (v1 >= 1.0f); v1 = s1v ? 0.f : v1;
      v2 += (h2 - v2) * 0.5f; bool s2v = (v2 >= 1.0f); v2 = s2v ? 0.f : v2;
      v3 += (h3 - v3) * 0.5f; bool s3v = (v3 >= 1.0f); v3 = s3v ? 0.f : v3;
      uint32_t pk = (s0 ? 1u : 0u) | (s1v ? 0x100u : 0u)
                  | (s2v ? 0x10000u : 0u) | (s3v ? 0x1000000u : 0u);
      uint32_t chunk = ((ch0 >> 4) * 4u + (uint32_t)t) * NCOL + n;
      *(uint32_t*)((char*)s2 + (size_t)chunk * 16u + (size_t)(ch0 & 15u)) = pk;
    }
  }
}

// ---------------------------------------------------------------------------
// GEMM2 (i8, B-only dbuf): M=512, K=2048, BK=128 i8, 16 K-tiles, tile
// 128M x (64n x 4t). LDS 80KB = A 16KB single + B 2x32KB -> 2 blocks/CU.
// Per iter: compute(k) -> lgkm0+bar -> issue A(k+1)[L2] + B(k+2)[HBM, into
// freed half] -> vmcnt(4) retires {B(k+1), A(k+1)} (B had a full iter of
// cover) -> bar. XCD swizzle (392 = 8x49).
#define G2_SB(kt, base) do { \
  _Pragma("unroll") for (uint32_t r = 0; r < 4; ++r) { \
    uint32_t cid = r * 512u + tid; \
    uint32_t kb = cid >> 8, rem = cid & 255u; \
    uint32_t tt = rem >> 6, dn = rem & 63u; \
    const char* src = (const char*)s2 \
        + (size_t)((((kt) * 8u + kb) * 4u + tt) * NCOL + n0 + dn) * 16u; \
    async16(src, (base) + (size_t)cid * 16u); \
  } \
} while (0)
#define G2_SA(kt) do { \
  _Pragma("unroll") for (uint32_t r = 0; r < 2; ++r) { \
    uint32_t cid = r * 512u + tid; \
    uint32_t i = cid >> 3, q = cid & 7u; \
    const char* src = (const char*)W2q + (size_t)(m0 + i) * 2048u \
        + (size_t)((kt) * 128u) + (size_t)((q ^ (i & 7u)) * 16u); \
    async16(src, lds + (size_t)cid * 16u); \
  } \
} while (0)

__launch_bounds__(512)
__global__ void gemm2_out_kernel(const signed char* __restrict__ W2q,
                                 const signed char* __restrict__ s2,
                                 const float* __restrict__ scale2,
                                 const float* __restrict__ bias2,
                                 const float* __restrict__ xin,
                                 float* __restrict__ outp) {
  extern __shared__ __align__(16) char lds[];   // A 16KB | B0 32KB | B1 32KB
  float* ep = (float*)lds;
  const uint32_t tid = threadIdx.x;
  const uint32_t wid = tid >> 6;
  const uint32_t lane = tid & 63u;
  const uint32_t il = lane & 15u, g = lane >> 4;
  const uint32_t wm = wid >> 2, wn = wid & 3u;
  const uint32_t bid = blockIdx.x;
  const uint32_t lid = (bid & 7u) * 49u + (bid >> 3);
  const uint32_t m0 = (lid & 3u) * 128u;
  const uint32_t n0 = (lid >> 2) * 64u;

  i32x4 acc[4][4];
  #pragma unroll
  for (int i = 0; i < 4; ++i)
    #pragma unroll
    for (int j = 0; j < 4; ++j) acc[i][j] = (i32x4){0, 0, 0, 0};

  // prologue: B(0)->buf0, A(0), B(1)->buf1; await B(0)+A(0); B(1) in flight
  G2_SB(0u, lds + 16384u);
  G2_SA(0u);
  G2_SB(1u, lds + 49152u);
  VMW(4);
  RBAR();

  for (uint32_t kt = 0; kt < 16u; ++kt) {
    const char* ldsA = lds;
    const char* ldsB = lds + 16384u + (kt & 1u) * 32768u;
    #pragma unroll
    for (int ks = 0; ks < 2; ++ks) {
      i32x4 af[4], bfr0, bfr1;
      #pragma unroll
      for (int fm = 0; fm < 4; ++fm) {
        uint32_t i = wm * 64u + (uint32_t)fm * 16u + il;
        uint32_t q = (uint32_t)ks * 4u + g;
        af[fm] = *(const i32x4*)(ldsA + (i * 8u + (q ^ (i & 7u))) * 16u);
      }
      #pragma unroll
      for (int th = 0; th < 2; ++th) {
        uint32_t chb = ((((uint32_t)ks * 4u + g) * 4u + (uint32_t)th * 2u) * 64u
                        + wn * 16u + il) * 16u;
        bfr0 = *(const i32x4*)(ldsB + chb);
        bfr1 = *(const i32x4*)(ldsB + chb + 1024u);
        #pragma unroll
        for (int fm = 0; fm < 4; ++fm) {
          acc[fm][th*2]   = MFMA_I8(af[fm], bfr0, acc[fm][th*2], 0, 0, 0);
          acc[fm][th*2+1] = MFMA_I8(af[fm], bfr1, acc[fm][th*2+1], 0, 0, 0);
        }
      }
    }
    LGK0();              // this wave's reads of A-buf and B-buf[kt&1] done
    RBAR();              // ALL waves done -> safe to restage A and B[kt&1]
    if (kt + 1u < 16u) {
      G2_SA(kt + 1u);    // A(k+1) from L2 (~250cy), awaited below
      if (kt + 2u < 16u) {
        G2_SB(kt + 2u, lds + 16384u + (kt & 1u) * 32768u);  // into freed half
        VMW(4);          // retires B(k+1)[4]+A(k+1)[2]; B(k+2)[4] in flight
      } else {
        VMW(0);          // tail: drain everything
      }
      RBAR();
    }
  }

  // epilogue: dequant+BN2 (folded) + residual, LDS transpose -> float4 stores
  const uint32_t cl = lane >> 2, qq = lane & 3u;
  #pragma unroll
  for (int fm = 0; fm < 4; ++fm) {
    const uint32_t cbase2 = m0 + wm * 64u + (uint32_t)fm * 16u;
    f32x4 sc = *(const f32x4*)&scale2[cbase2 + 4u * g];
    f32x4 bi = *(const f32x4*)&bias2[cbase2 + 4u * g];
    #pragma unroll
    for (int t = 0; t < 4; ++t)
      #pragma unroll
      for (int r = 0; r < 4; ++r)
        ep[wid * 1280u + ((4u * g + (uint32_t)r) * 4u + (uint32_t)t) * 20u + il]
            = (float)acc[fm][t][r] * sc[r] + bi[r];
    __syncthreads();
    #pragma unroll
    for (int t = 0; t < 4; ++t) {
      f32x4 val = *(const f32x4*)&ep[wid * 1280u + (cl * 4u + (uint32_t)t) * 20u + qq * 4u];
      uint32_t nn = n0 + wn * 16u + qq * 4u;
      uint32_t b = nn / 196u, hw = nn - b * 196u;
      uint32_t c = cbase2 + cl;
      size_t off = (((size_t)t * 32u + b) * 512u + c) * 196u + hw;
      f32x4 iv = *(const f32x4*)(xin + off);
      *(f32x4*)(outp + off) = val + iv;
    }
    __syncthreads();
  }
}

// ---------------------------------------------------------------------------
extern "C" void kernel_launch(void* const* d_in, const int* in_sizes, int n_in,
                              void* d_out, int out_size, void* d_ws, size_t ws_size,
                              hipStream_t stream) {
  const float* x  = (const float*)d_in[0];
  const float* W1 = (const float*)d_in[1];
  const float* g1 = (const float*)d_in[2];
  const float* b1 = (const float*)d_in[3];
  const float* m1 = (const float*)d_in[4];
  const float* v1 = (const float*)d_in[5];
  const float* W2 = (const float*)d_in[6];
  const float* g2 = (const float*)d_in[7];
  const float* b2 = (const float*)d_in[8];
  const float* m2 = (const float*)d_in[9];
  const float* v2 = (const float*)d_in[10];
  float* out = (float*)d_out;
  char* ws = (char*)d_ws;

  signed char* s2b    = (signed char*)(ws);               //  51,380,224 B [128][4][6272][16] i8
  signed char* s1b    = (signed char*)(ws + 102760448);   //  12,845,056 B [32][4][6272][16] i8
  signed char* W1q    = (signed char*)(ws + 128450560);   //   1,048,576 B [2048][512] i8
  signed char* W2q    = (signed char*)(ws + 132644864);   //   1,048,576 B [512][2048] i8
  float*       scale1 = (float*)(ws + 134742016);
  float*       bias1  = (float*)(ws + 134750208);
  float*       scale2 = (float*)(ws + 134758400);
  float*       bias2  = (float*)(ws + 134760448);

  (void)hipFuncSetAttribute((const void*)gemm2_out_kernel,
                            hipFuncAttributeMaxDynamicSharedMemorySize, 81920);

  prep1_kernel<<<2048, 256, 0, stream>>>(W1, g1, b1, m1, v1, W1q, scale1, bias1);
  prep2_kernel<<<512, 256, 0, stream>>>(W2, g2, b2, m2, v2, W2q, scale2, bias2);
  lif1_kernel<<<dim3(8, 98), 256, 0, stream>>>(x, s1b);
  gemm1_lif2_kernel<<<1568, 512, 0, stream>>>(W1q, s1b, scale1, bias1, s2b);
  gemm2_out_kernel<<<392, 512, 81920, stream>>>(W2q, s2b, scale2, bias2, x, out);
}

// Round 19
// 104.633 us; speedup vs baseline: 1.1461x; 1.1461x over previous
//
#include <hip/hip_runtime.h>
#include <stdint.h>

// LIF -> 1x1conv(512->2048) -> BN -> LIF -> 1x1conv(2048->512) -> BN -> +x
// T=4 B=32 C=512 Ch=2048 HW=196.
// R19 = R11 verbatim (104.5us global best). Both GEMMs i8 MFMA (16x16x64),
// per-row-quant W1/W2 (dequant folded into BN), i8 spikes {0,1}, shallow
// 2-barrier K-loops with proven XOR LDS layouts, XCD swizzle.

typedef float f32x4 __attribute__((ext_vector_type(4)));
typedef int i32x4 __attribute__((ext_vector_type(4)));

#define TPLANE 3211264u     // B*C*HW
#define NCOL   6272u        // B*HW
#define MFMA_I8 __builtin_amdgcn_mfma_i32_16x16x64_i8

static __device__ __forceinline__ void async16(const void* g, void* l) {
  __builtin_amdgcn_global_load_lds((const __attribute__((address_space(1))) uint32_t*)g,
                                   (__attribute__((address_space(3))) uint32_t*)l, 16, 0, 0);
}

// ---------------------------------------------------------------------------
// prep1: W1 -> per-row i8 [2048][512]; quant scale folded into BN1 scale.
__global__ void prep1_kernel(const float* __restrict__ W1,
                             const float* __restrict__ g1, const float* __restrict__ b1,
                             const float* __restrict__ m1, const float* __restrict__ v1,
                             signed char* __restrict__ W1q,
                             float* __restrict__ scale1, float* __restrict__ bias1) {
  __shared__ float red[256];
  const uint32_t c = blockIdx.x, tid = threadIdx.x;   // 2048 blocks x 256 thr
  const float* row = W1 + (size_t)c * 512u;
  float v0 = row[tid], v1l = row[tid + 256u];
  float mx = fmaxf(fabsf(v0), fabsf(v1l));
  red[tid] = mx; __syncthreads();
  for (uint32_t s = 128u; s > 0u; s >>= 1) {
    if (tid < s) red[tid] = fmaxf(red[tid], red[tid + s]);
    __syncthreads();
  }
  const float rmax = red[0];
  const float inv = rmax > 0.f ? 127.f / rmax : 0.f;
  W1q[(size_t)c * 512u + tid]        = (signed char)__float2int_rn(v0 * inv);
  W1q[(size_t)c * 512u + tid + 256u] = (signed char)__float2int_rn(v1l * inv);
  if (tid == 0) {
    float bn = g1[c] / sqrtf(v1[c] + 1e-5f);
    scale1[c] = (rmax / 127.f) * bn;          // dequant folded
    bias1[c]  = b1[c] - m1[c] * bn;
  }
}

// ---------------------------------------------------------------------------
// prep2: W2 -> per-row i8 quant [512][2048]; quant scale folded into BN2.
__global__ void prep2_kernel(const float* __restrict__ W2,
                             const float* __restrict__ g2, const float* __restrict__ b2,
                             const float* __restrict__ m2, const float* __restrict__ v2,
                             signed char* __restrict__ W2q,
                             float* __restrict__ scale2, float* __restrict__ bias2) {
  __shared__ float red[256];
  const uint32_t c = blockIdx.x, tid = threadIdx.x;
  const float* row = W2 + (size_t)c * 2048u;
  float vals[8];
  float mx = 0.f;
  #pragma unroll
  for (int j = 0; j < 8; ++j) {
    vals[j] = row[tid + 256u * (uint32_t)j];
    mx = fmaxf(mx, fabsf(vals[j]));
  }
  red[tid] = mx; __syncthreads();
  for (uint32_t s = 128u; s > 0u; s >>= 1) {
    if (tid < s) red[tid] = fmaxf(red[tid], red[tid + s]);
    __syncthreads();
  }
  const float rmax = red[0];
  const float inv = rmax > 0.f ? 127.f / rmax : 0.f;
  #pragma unroll
  for (int j = 0; j < 8; ++j)
    W2q[(size_t)c * 2048u + tid + 256u * (uint32_t)j] =
        (signed char)__float2int_rn(vals[j] * inv);
  if (tid == 0) {
    float bn = g2[c] / sqrtf(v2[c] + 1e-5f);
    scale2[c] = (rmax / 127.f) * bn;
    bias2[c]  = b2[c] - m2[c] * bn;
  }
}

// ---------------------------------------------------------------------------
// LIF over input (bit-exact fp32), spikes i8 {0,1} in K-blocked layout:
// chunk = (cb16*4 + t)*NCOL + n; 16B chunk = 16 consecutive channels.
__global__ void lif1_kernel(const float* __restrict__ x, signed char* __restrict__ s1) {
  __shared__ __align__(16) uint16_t sl[64 * 66 * 4];   // [c:64][n:66 pad][t:4], value 0/1
  const uint32_t tid = threadIdx.x;
  const uint32_t c0 = blockIdx.x * 64u;
  const uint32_t n0 = blockIdx.y * 64u;
  #pragma unroll
  for (int j = 0; j < 16; ++j) {
    uint32_t idx = (uint32_t)j * 256u + tid;
    uint32_t cl = idx >> 6, nl = idx & 63u;
    uint32_t n = n0 + nl;
    uint32_t b = n / 196u, hw = n - b * 196u;
    const float* px = x + (size_t)(b * 512u + c0 + cl) * 196u + hw;
    float v = 0.f;
    uint16_t sp[4];
    #pragma unroll
    for (int t = 0; t < 4; ++t) {
      float xv = px[(size_t)t * TPLANE];
      v += (xv - v) * 0.5f;                // exact: *0.5 never rounds
      bool s = (v >= 1.0f);
      sp[t] = s ? (uint16_t)1u : (uint16_t)0u;
      v = s ? 0.f : v;
    }
    uint2 pk;
    pk.x = (uint32_t)sp[0] | ((uint32_t)sp[1] << 16);
    pk.y = (uint32_t)sp[2] | ((uint32_t)sp[3] << 16);
    *(uint2*)&sl[(cl * 66u + nl) * 4u] = pk;
  }
  __syncthreads();
  // consumer: pack 16 channels (bytes) per chunk at fixed (t, n)
  #pragma unroll
  for (int j = 0; j < 4; ++j) {
    uint32_t id = (uint32_t)j * 256u + tid;              // 1024 chunks
    uint32_t nl = id & 63u, t = (id >> 6) & 3u, cb = id >> 8;   // cb: 0..3
    uint32_t us[4];
    #pragma unroll
    for (int w = 0; w < 4; ++w) {
      uint32_t b0 = sl[((cb * 16u + (uint32_t)w * 4u + 0u) * 66u + nl) * 4u + t];
      uint32_t b1 = sl[((cb * 16u + (uint32_t)w * 4u + 1u) * 66u + nl) * 4u + t];
      uint32_t b2 = sl[((cb * 16u + (uint32_t)w * 4u + 2u) * 66u + nl) * 4u + t];
      uint32_t b3 = sl[((cb * 16u + (uint32_t)w * 4u + 3u) * 66u + nl) * 4u + t];
      us[w] = b0 | (b1 << 8) | (b2 << 16) | (b3 << 24);
    }
    uint32_t chunk = (((c0 >> 4) + cb) * 4u + t) * NCOL + n0 + nl;
    uint4 o4; o4.x = us[0]; o4.y = us[1]; o4.z = us[2]; o4.w = us[3];
    *(uint4*)(s1 + (size_t)chunk * 16u) = o4;
  }
}

// ---------------------------------------------------------------------------
// GEMM1 (i8): M=2048, K=512 (BK=128 i8, 4 K-tiles), N-strip 64n x 4t,
// 48KB LDS, 32 MFMA/wave/barrier-pair. Fused dequant+BN1 + in-register
// LIF2 scan -> s2 i8 spike bytes. XCD swizzle over 1568 = 8x196 blocks.
__launch_bounds__(512)
__global__ void gemm1_lif2_kernel(const signed char* __restrict__ W1q,
                                  const signed char* __restrict__ s1,
                                  const float* __restrict__ scale1,
                                  const float* __restrict__ bias1,
                                  signed char* __restrict__ s2) {
  __shared__ __align__(16) char lds[49152];
  char* ldsA = lds;               // 16KB: [i:128][q':8]*16B, q' = q ^ (i&7)
  char* ldsB = lds + 16384;       // 32KB: [kb:8][t:4][dn:64]*16B
  const uint32_t tid = threadIdx.x;
  const uint32_t wid = tid >> 6;
  const uint32_t lane = tid & 63u;
  const uint32_t il = lane & 15u, g = lane >> 4;
  const uint32_t wm = wid >> 2, wn = wid & 3u;
  const uint32_t bid = blockIdx.x;
  const uint32_t lid = (bid & 7u) * 196u + (bid >> 3);   // 1568 = 8*196
  const uint32_t m0 = (lid & 15u) * 128u;                // 16 M-blocks
  const uint32_t n0 = (lid >> 4) * 64u;                  // 98 N-blocks

  i32x4 acc[4][4];                // [fm][t]
  #pragma unroll
  for (int i = 0; i < 4; ++i)
    #pragma unroll
    for (int j = 0; j < 4; ++j) acc[i][j] = (i32x4){0, 0, 0, 0};

  for (int kt = 0; kt < 4; ++kt) {
    #pragma unroll
    for (uint32_t r = 0; r < 4; ++r) {     // B tile: 2048 16B chunks
      uint32_t cid = r * 512u + tid;
      uint32_t kb = cid >> 8, rem = cid & 255u;
      uint32_t tt = rem >> 6, dn = rem & 63u;
      const char* src = (const char*)s1
          + (size_t)((((uint32_t)kt * 8u + kb) * 4u + tt) * NCOL + n0 + dn) * 16u;
      async16(src, ldsB + (size_t)cid * 16u);
    }
    #pragma unroll
    for (uint32_t r = 0; r < 2; ++r) {     // A tile: 1024 16B chunks
      uint32_t cid = r * 512u + tid;
      uint32_t i = cid >> 3, q = cid & 7u;
      const char* src = (const char*)W1q + (size_t)(m0 + i) * 512u
                        + (size_t)((uint32_t)kt * 128u) + (size_t)((q ^ (i & 7u)) * 16u);
      async16(src, ldsA + (size_t)cid * 16u);
    }
    __syncthreads();
    #pragma unroll
    for (int ks = 0; ks < 2; ++ks) {       // two K=64 halves of BK=128
      i32x4 af[4], bfr0, bfr1;
      #pragma unroll
      for (int fm = 0; fm < 4; ++fm) {
        uint32_t i = wm * 64u + (uint32_t)fm * 16u + il;
        uint32_t q = (uint32_t)ks * 4u + g;
        af[fm] = *(const i32x4*)(ldsA + (i * 8u + (q ^ (i & 7u))) * 16u);
      }
      #pragma unroll
      for (int th = 0; th < 2; ++th) {
        uint32_t chb = ((((uint32_t)ks * 4u + g) * 4u + (uint32_t)th * 2u) * 64u
                        + wn * 16u + il) * 16u;
        bfr0 = *(const i32x4*)(ldsB + chb);
        bfr1 = *(const i32x4*)(ldsB + chb + 1024u);
        #pragma unroll
        for (int fm = 0; fm < 4; ++fm) {
          acc[fm][th*2]   = MFMA_I8(af[fm], bfr0, acc[fm][th*2], 0, 0, 0);
          acc[fm][th*2+1] = MFMA_I8(af[fm], bfr1, acc[fm][th*2+1], 0, 0, 0);
        }
      }
    }
    __syncthreads();
  }

  // epilogue: dequant+BN1 (folded) + in-register LIF2 scan -> s2 i8 bytes
  const uint32_t n = n0 + wn * 16u + il;
  #pragma unroll
  for (int fm = 0; fm < 4; ++fm) {
    const uint32_t ch0 = m0 + wm * 64u + (uint32_t)fm * 16u + 4u * g;
    f32x4 sc = *(const f32x4*)&scale1[ch0];
    f32x4 bi = *(const f32x4*)&bias1[ch0];
    float v0 = 0.f, v1 = 0.f, v2 = 0.f, v3 = 0.f;
    #pragma unroll
    for (int t = 0; t < 4; ++t) {
      float h0 = (float)acc[fm][t][0] * sc[0] + bi[0];
      float h1 = (float)acc[fm][t][1] * sc[1] + bi[1];
      float h2 = (float)acc[fm][t][2] * sc[2] + bi[2];
      float h3 = (float)acc[fm][t][3] * sc[3] + bi[3];
      v0 += (h0 - v0) * 0.5f; bool s0 = (v0 >= 1.0f); v0 = s0 ? 0.f : v0;
      v1 += (h1 - v1) * 0.5f; bool s1v = (v1 >= 1.0f); v1 = s1v ? 0.f : v1;
      v2 += (h2 - v2) * 0.5f; bool s2v = (v2 >= 1.0f); v2 = s2v ? 0.f : v2;
      v3 += (h3 - v3) * 0.5f; bool s3v = (v3 >= 1.0f); v3 = s3v ? 0.f : v3;
      uint32_t pk = (s0 ? 1u : 0u) | (s1v ? 0x100u : 0u)
                  | (s2v ? 0x10000u : 0u) | (s3v ? 0x1000000u : 0u);
      uint32_t chunk = ((ch0 >> 4) * 4u + (uint32_t)t) * NCOL + n;
      *(uint32_t*)((char*)s2 + (size_t)chunk * 16u + (size_t)(ch0 & 15u)) = pk;
    }
  }
}

// ---------------------------------------------------------------------------
// GEMM2 (i8): M=512, K=2048, BK=128 i8, 16 K-tiles, 48KB LDS, shallow
// 2-barrier loop (the proven fastest of 6 variants). Fused dequant+BN2 +
// residual + LDS-transpose float4 stores. XCD swizzle (392 = 8x49).
__launch_bounds__(512)
__global__ void gemm2_out_kernel(const signed char* __restrict__ W2q,
                                 const signed char* __restrict__ s2,
                                 const float* __restrict__ scale2,
                                 const float* __restrict__ bias2,
                                 const float* __restrict__ xin,
                                 float* __restrict__ outp) {
  __shared__ __align__(16) char lds[49152];
  char* ldsA = lds;               // 16KB: [i:128][q':8]*16B
  char* ldsB = lds + 16384;       // 32KB: [kb:8][t:4][dn:64]*16B
  float* ep = (float*)lds;
  const uint32_t tid = threadIdx.x;
  const uint32_t wid = tid >> 6;
  const uint32_t lane = tid & 63u;
  const uint32_t il = lane & 15u, g = lane >> 4;
  const uint32_t wm = wid >> 2, wn = wid & 3u;
  const uint32_t bid = blockIdx.x;
  const uint32_t lid = (bid & 7u) * 49u + (bid >> 3);
  const uint32_t m0 = (lid & 3u) * 128u;
  const uint32_t n0 = (lid >> 2) * 64u;

  i32x4 acc[4][4];
  #pragma unroll
  for (int i = 0; i < 4; ++i)
    #pragma unroll
    for (int j = 0; j < 4; ++j) acc[i][j] = (i32x4){0, 0, 0, 0};

  for (int kt = 0; kt < 16; ++kt) {
    #pragma unroll
    for (uint32_t r = 0; r < 4; ++r) {     // B tile first (HBM): 2048 chunks
      uint32_t cid = r * 512u + tid;
      uint32_t kb = cid >> 8, rem = cid & 255u;
      uint32_t tt = rem >> 6, dn = rem & 63u;
      const char* src = (const char*)s2
          + (size_t)((((uint32_t)kt * 8u + kb) * 4u + tt) * NCOL + n0 + dn) * 16u;
      async16(src, ldsB + (size_t)cid * 16u);
    }
    #pragma unroll
    for (uint32_t r = 0; r < 2; ++r) {     // A tile (L2): 1024 chunks
      uint32_t cid = r * 512u + tid;
      uint32_t i = cid >> 3, q = cid & 7u;
      const char* src = (const char*)W2q + (size_t)(m0 + i) * 2048u
                        + (size_t)((uint32_t)kt * 128u) + (size_t)((q ^ (i & 7u)) * 16u);
      async16(src, ldsA + (size_t)cid * 16u);
    }
    __syncthreads();
    #pragma unroll
    for (int ks = 0; ks < 2; ++ks) {
      i32x4 af[4], bfr0, bfr1;
      #pragma unroll
      for (int fm = 0; fm < 4; ++fm) {
        uint32_t i = wm * 64u + (uint32_t)fm * 16u + il;
        uint32_t q = (uint32_t)ks * 4u + g;
        af[fm] = *(const i32x4*)(ldsA + (i * 8u + (q ^ (i & 7u))) * 16u);
      }
      #pragma unroll
      for (int th = 0; th < 2; ++th) {
        uint32_t chb = ((((uint32_t)ks * 4u + g) * 4u + (uint32_t)th * 2u) * 64u
                        + wn * 16u + il) * 16u;
        bfr0 = *(const i32x4*)(ldsB + chb);
        bfr1 = *(const i32x4*)(ldsB + chb + 1024u);
        #pragma unroll
        for (int fm = 0; fm < 4; ++fm) {
          acc[fm][th*2]   = MFMA_I8(af[fm], bfr0, acc[fm][th*2], 0, 0, 0);
          acc[fm][th*2+1] = MFMA_I8(af[fm], bfr1, acc[fm][th*2+1], 0, 0, 0);
        }
      }
    }
    __syncthreads();
  }

  // epilogue: dequant+BN2 (folded) + residual, LDS transpose -> float4 stores
  const uint32_t cl = lane >> 2, qq = lane & 3u;
  #pragma unroll
  for (int fm = 0; fm < 4; ++fm) {
    const uint32_t cbase = m0 + wm * 64u + (uint32_t)fm * 16u;
    f32x4 sc = *(const f32x4*)&scale2[cbase + 4u * g];
    f32x4 bi = *(const f32x4*)&bias2[cbase + 4u * g];
    #pragma unroll
    for (int t = 0; t < 4; ++t)
      #pragma unroll
      for (int r = 0; r < 4; ++r)
        ep[wid * 1280u + ((4u * g + (uint32_t)r) * 4u + (uint32_t)t) * 20u + il]
            = (float)acc[fm][t][r] * sc[r] + bi[r];
    __syncthreads();
    #pragma unroll
    for (int t = 0; t < 4; ++t) {
      f32x4 val = *(const f32x4*)&ep[wid * 1280u + (cl * 4u + (uint32_t)t) * 20u + qq * 4u];
      uint32_t nn = n0 + wn * 16u + qq * 4u;
      uint32_t b = nn / 196u, hw = nn - b * 196u;
      uint32_t c = cbase + cl;
      size_t off = (((size_t)t * 32u + b) * 512u + c) * 196u + hw;
      f32x4 iv = *(const f32x4*)(xin + off);
      *(f32x4*)(outp + off) = val + iv;
    }
    __syncthreads();
  }
}

// ---------------------------------------------------------------------------
extern "C" void kernel_launch(void* const* d_in, const int* in_sizes, int n_in,
                              void* d_out, int out_size, void* d_ws, size_t ws_size,
                              hipStream_t stream) {
  const float* x  = (const float*)d_in[0];
  const float* W1 = (const float*)d_in[1];
  const float* g1 = (const float*)d_in[2];
  const float* b1 = (const float*)d_in[3];
  const float* m1 = (const float*)d_in[4];
  const float* v1 = (const float*)d_in[5];
  const float* W2 = (const float*)d_in[6];
  const float* g2 = (const float*)d_in[7];
  const float* b2 = (const float*)d_in[8];
  const float* m2 = (const float*)d_in[9];
  const float* v2 = (const float*)d_in[10];
  float* out = (float*)d_out;
  char* ws = (char*)d_ws;

  signed char* s2b    = (signed char*)(ws);               //  51,380,224 B [128][4][6272][16] i8
  signed char* s1b    = (signed char*)(ws + 102760448);   //  12,845,056 B [32][4][6272][16] i8
  signed char* W1q    = (signed char*)(ws + 128450560);   //   1,048,576 B [2048][512] i8
  signed char* W2q    = (signed char*)(ws + 132644864);   //   1,048,576 B [512][2048] i8
  float*       scale1 = (float*)(ws + 134742016);
  float*       bias1  = (float*)(ws + 134750208);
  float*       scale2 = (float*)(ws + 134758400);
  float*       bias2  = (float*)(ws + 134760448);

  prep1_kernel<<<2048, 256, 0, stream>>>(W1, g1, b1, m1, v1, W1q, scale1, bias1);
  prep2_kernel<<<512, 256, 0, stream>>>(W2, g2, b2, m2, v2, W2q, scale2, bias2);
  lif1_kernel<<<dim3(8, 98), 256, 0, stream>>>(x, s1b);
  gemm1_lif2_kernel<<<1568, 512, 0, stream>>>(W1q, s1b, scale1, bias1, s2b);
  gemm2_out_kernel<<<392, 512, 0, stream>>>(W2q, s2b, scale2, bias2, x, out);
}

// Round 20
// 102.274 us; speedup vs baseline: 1.1725x; 1.0231x over previous
//
#include <hip/hip_runtime.h>
#include <stdint.h>

// LIF -> 1x1conv(512->2048) -> BN -> LIF -> 1x1conv(2048->512) -> BN -> +x
// T=4 B=32 C=512 Ch=2048 HW=196.
// R20 = R11/R19 skeleton + SEMI-PACKED spikes (4 channel-bits per byte):
// s1 3.2MB, s2 12.8MB; GEMM B-staging halves (16B chunk = 64 channels);
// unpack at MFMA-read via ((b>>8j)&0xF)*0x00204081&0x01010101 (3 VALU/u32).
// Same i8 MFMA math -> bit-identical output.

typedef float f32x4 __attribute__((ext_vector_type(4)));
typedef int i32x4 __attribute__((ext_vector_type(4)));

#define TPLANE 3211264u     // B*C*HW
#define NCOL   6272u        // B*HW
#define MFMA_I8 __builtin_amdgcn_mfma_i32_16x16x64_i8

static __device__ __forceinline__ void async16(const void* g, void* l) {
  __builtin_amdgcn_global_load_lds((const __attribute__((address_space(1))) uint32_t*)g,
                                   (__attribute__((address_space(3))) uint32_t*)l, 16, 0, 0);
}
// expand 16 packed channel-bits (4 bits/byte in u32) -> 16 i8 bytes {0,1}
static __device__ __forceinline__ i32x4 expand16(uint32_t b) {
  i32x4 v;
  v[0] = (int)((((b       ) & 0xFu) * 0x00204081u) & 0x01010101u);
  v[1] = (int)((((b >>  8u) & 0xFu) * 0x00204081u) & 0x01010101u);
  v[2] = (int)((((b >> 16u) & 0xFu) * 0x00204081u) & 0x01010101u);
  v[3] = (int)((((b >> 24u) & 0xFu) * 0x00204081u) & 0x01010101u);
  return v;
}

// ---------------------------------------------------------------------------
// prep1: W1 -> per-row i8 [2048][512]; quant scale folded into BN1 scale.
__global__ void prep1_kernel(const float* __restrict__ W1,
                             const float* __restrict__ g1, const float* __restrict__ b1,
                             const float* __restrict__ m1, const float* __restrict__ v1,
                             signed char* __restrict__ W1q,
                             float* __restrict__ scale1, float* __restrict__ bias1) {
  __shared__ float red[256];
  const uint32_t c = blockIdx.x, tid = threadIdx.x;
  const float* row = W1 + (size_t)c * 512u;
  float v0 = row[tid], v1l = row[tid + 256u];
  float mx = fmaxf(fabsf(v0), fabsf(v1l));
  red[tid] = mx; __syncthreads();
  for (uint32_t s = 128u; s > 0u; s >>= 1) {
    if (tid < s) red[tid] = fmaxf(red[tid], red[tid + s]);
    __syncthreads();
  }
  const float rmax = red[0];
  const float inv = rmax > 0.f ? 127.f / rmax : 0.f;
  W1q[(size_t)c * 512u + tid]        = (signed char)__float2int_rn(v0 * inv);
  W1q[(size_t)c * 512u + tid + 256u] = (signed char)__float2int_rn(v1l * inv);
  if (tid == 0) {
    float bn = g1[c] / sqrtf(v1[c] + 1e-5f);
    scale1[c] = (rmax / 127.f) * bn;
    bias1[c]  = b1[c] - m1[c] * bn;
  }
}

// ---------------------------------------------------------------------------
// prep2: W2 -> per-row i8 quant [512][2048]; quant scale folded into BN2.
__global__ void prep2_kernel(const float* __restrict__ W2,
                             const float* __restrict__ g2, const float* __restrict__ b2,
                             const float* __restrict__ m2, const float* __restrict__ v2,
                             signed char* __restrict__ W2q,
                             float* __restrict__ scale2, float* __restrict__ bias2) {
  __shared__ float red[256];
  const uint32_t c = blockIdx.x, tid = threadIdx.x;
  const float* row = W2 + (size_t)c * 2048u;
  float vals[8];
  float mx = 0.f;
  #pragma unroll
  for (int j = 0; j < 8; ++j) {
    vals[j] = row[tid + 256u * (uint32_t)j];
    mx = fmaxf(mx, fabsf(vals[j]));
  }
  red[tid] = mx; __syncthreads();
  for (uint32_t s = 128u; s > 0u; s >>= 1) {
    if (tid < s) red[tid] = fmaxf(red[tid], red[tid + s]);
    __syncthreads();
  }
  const float rmax = red[0];
  const float inv = rmax > 0.f ? 127.f / rmax : 0.f;
  #pragma unroll
  for (int j = 0; j < 8; ++j)
    W2q[(size_t)c * 2048u + tid + 256u * (uint32_t)j] =
        (signed char)__float2int_rn(vals[j] * inv);
  if (tid == 0) {
    float bn = g2[c] / sqrtf(v2[c] + 1e-5f);
    scale2[c] = (rmax / 127.f) * bn;
    bias2[c]  = b2[c] - m2[c] * bn;
  }
}

// ---------------------------------------------------------------------------
// LIF (bit-exact fp32), spikes packed 4 ch/byte. Chunk 16B = 64 channels at
// (t,n): chunk = (cb64*4 + t)*NCOL + n. Block covers exactly 64 channels.
__global__ void lif1_kernel(const float* __restrict__ x, signed char* __restrict__ s1) {
  __shared__ __align__(16) uint16_t sl[64 * 66 * 4];   // [c:64][n:66 pad][t:4], 0/1
  const uint32_t tid = threadIdx.x;
  const uint32_t c0 = blockIdx.x * 64u;
  const uint32_t n0 = blockIdx.y * 64u;
  #pragma unroll
  for (int j = 0; j < 16; ++j) {
    uint32_t idx = (uint32_t)j * 256u + tid;
    uint32_t cl = idx >> 6, nl = idx & 63u;
    uint32_t n = n0 + nl;
    uint32_t b = n / 196u, hw = n - b * 196u;
    const float* px = x + (size_t)(b * 512u + c0 + cl) * 196u + hw;
    float v = 0.f;
    uint16_t sp[4];
    #pragma unroll
    for (int t = 0; t < 4; ++t) {
      float xv = px[(size_t)t * TPLANE];
      v += (xv - v) * 0.5f;                // exact: *0.5 never rounds
      bool s = (v >= 1.0f);
      sp[t] = s ? (uint16_t)1u : (uint16_t)0u;
      v = s ? 0.f : v;
    }
    uint2 pk;
    pk.x = (uint32_t)sp[0] | ((uint32_t)sp[1] << 16);
    pk.y = (uint32_t)sp[2] | ((uint32_t)sp[3] << 16);
    *(uint2*)&sl[(cl * 66u + nl) * 4u] = pk;
  }
  __syncthreads();
  // consumer: 256 chunks (4t x 64n), each 16B = 64 channels, 4 bits/byte
  {
    uint32_t nl = tid & 63u, t = tid >> 6;           // t: 0..3
    uint32_t us[4];
    #pragma unroll
    for (int w = 0; w < 4; ++w) {                    // u32 = 16 channels
      uint32_t acc = 0;
      #pragma unroll
      for (int bby = 0; bby < 4; ++bby)              // byte = 4 channels
        #pragma unroll
        for (int r = 0; r < 4; ++r)
          acc |= (uint32_t)sl[(((uint32_t)(w * 16 + bby * 4 + r)) * 66u + nl) * 4u + t]
                 << (8 * bby + r);
      us[w] = acc;
    }
    uint32_t chunk = ((c0 >> 6) * 4u + t) * NCOL + n0 + nl;
    uint4 o4; o4.x = us[0]; o4.y = us[1]; o4.z = us[2]; o4.w = us[3];
    *(uint4*)(s1 + (size_t)chunk * 16u) = o4;
  }
}

// ---------------------------------------------------------------------------
// GEMM1 (i8, packed-B): M=2048, K=512 (BK=128 = 2 cb64 per tile, 4 K-tiles),
// N-strip 64n x 4t. LDS 24KB (A 16K + packed B 8K). Unpack at MFMA-read.
// Fused dequant+BN1 + in-register LIF2 scan -> s2 packed bytes. XCD swizzle.
__launch_bounds__(512)
__global__ void gemm1_lif2_kernel(const signed char* __restrict__ W1q,
                                  const signed char* __restrict__ s1,
                                  const float* __restrict__ scale1,
                                  const float* __restrict__ bias1,
                                  signed char* __restrict__ s2) {
  __shared__ __align__(16) char lds[24576];
  char* ldsA = lds;               // 16KB: [i:128][q':8]*16B, q' = q ^ (i&7)
  char* ldsB = lds + 16384;       // 8KB packed: [cb:2][t:4][dn:64]*16B
  const uint32_t tid = threadIdx.x;
  const uint32_t wid = tid >> 6;
  const uint32_t lane = tid & 63u;
  const uint32_t il = lane & 15u, g = lane >> 4;
  const uint32_t wm = wid >> 2, wn = wid & 3u;
  const uint32_t bid = blockIdx.x;
  const uint32_t lid = (bid & 7u) * 196u + (bid >> 3);   // 1568 = 8*196
  const uint32_t m0 = (lid & 15u) * 128u;
  const uint32_t n0 = (lid >> 4) * 64u;

  i32x4 acc[4][4];                // [fm][t]
  #pragma unroll
  for (int i = 0; i < 4; ++i)
    #pragma unroll
    for (int j = 0; j < 4; ++j) acc[i][j] = (i32x4){0, 0, 0, 0};

  for (int kt = 0; kt < 4; ++kt) {
    {                                      // packed B tile: 512 chunks
      uint32_t cb = tid >> 8, rem = tid & 255u;
      uint32_t tt = rem >> 6, dn = rem & 63u;
      const char* src = (const char*)s1
          + (size_t)((((uint32_t)kt * 2u + cb) * 4u + tt) * NCOL + n0 + dn) * 16u;
      async16(src, ldsB + (size_t)tid * 16u);
    }
    #pragma unroll
    for (uint32_t r = 0; r < 2; ++r) {     // A tile: 1024 chunks
      uint32_t cid = r * 512u + tid;
      uint32_t i = cid >> 3, q = cid & 7u;
      const char* src = (const char*)W1q + (size_t)(m0 + i) * 512u
                        + (size_t)((uint32_t)kt * 128u) + (size_t)((q ^ (i & 7u)) * 16u);
      async16(src, ldsA + (size_t)cid * 16u);
    }
    __syncthreads();
    #pragma unroll
    for (int ks = 0; ks < 2; ++ks) {       // two K=64 halves of BK=128
      i32x4 af[4], bfr0, bfr1;
      #pragma unroll
      for (int fm = 0; fm < 4; ++fm) {
        uint32_t i = wm * 64u + (uint32_t)fm * 16u + il;
        uint32_t q = (uint32_t)ks * 4u + g;
        af[fm] = *(const i32x4*)(ldsA + (i * 8u + (q ^ (i & 7u))) * 16u);
      }
      #pragma unroll
      for (int th = 0; th < 2; ++th) {
        // packed u32 = 16 channels of k-group (ks*4+g) at (t, n)
        uint32_t pb = (((uint32_t)ks * 4u + (uint32_t)th * 2u) * 64u
                       + wn * 16u + il) * 16u + g * 4u;
        uint32_t b0 = *(const uint32_t*)(ldsB + pb);
        uint32_t b1 = *(const uint32_t*)(ldsB + pb + 1024u);   // t+1
        bfr0 = expand16(b0);
        bfr1 = expand16(b1);
        #pragma unroll
        for (int fm = 0; fm < 4; ++fm) {
          acc[fm][th*2]   = MFMA_I8(af[fm], bfr0, acc[fm][th*2], 0, 0, 0);
          acc[fm][th*2+1] = MFMA_I8(af[fm], bfr1, acc[fm][th*2+1], 0, 0, 0);
        }
      }
    }
    __syncthreads();
  }

  // epilogue: dequant+BN1 (folded) + in-register LIF2 scan -> packed byte
  // (4 channel-bits); 4fm x 4g lanes cover all 16 bytes of each chunk.
  const uint32_t n = n0 + wn * 16u + il;
  #pragma unroll
  for (int fm = 0; fm < 4; ++fm) {
    const uint32_t ch0 = m0 + wm * 64u + (uint32_t)fm * 16u + 4u * g;
    f32x4 sc = *(const f32x4*)&scale1[ch0];
    f32x4 bi = *(const f32x4*)&bias1[ch0];
    float v0 = 0.f, v1 = 0.f, v2 = 0.f, v3 = 0.f;
    #pragma unroll
    for (int t = 0; t < 4; ++t) {
      float h0 = (float)acc[fm][t][0] * sc[0] + bi[0];
      float h1 = (float)acc[fm][t][1] * sc[1] + bi[1];
      float h2 = (float)acc[fm][t][2] * sc[2] + bi[2];
      float h3 = (float)acc[fm][t][3] * sc[3] + bi[3];
      v0 += (h0 - v0) * 0.5f; bool s0 = (v0 >= 1.0f); v0 = s0 ? 0.f : v0;
      v1 += (h1 - v1) * 0.5f; bool s1v = (v1 >= 1.0f); v1 = s1v ? 0.f : v1;
      v2 += (h2 - v2) * 0.5f; bool s2v = (v2 >= 1.0f); v2 = s2v ? 0.f : v2;
      v3 += (h3 - v3) * 0.5f; bool s3v = (v3 >= 1.0f); v3 = s3v ? 0.f : v3;
      uint32_t pkb = (s0 ? 1u : 0u) | (s1v ? 2u : 0u)
                   | (s2v ? 4u : 0u) | (s3v ? 8u : 0u);
      uint32_t chunk = ((ch0 >> 6) * 4u + (uint32_t)t) * NCOL + n;
      ((uint8_t*)s2)[(size_t)chunk * 16u + ((ch0 & 63u) >> 2)] = (uint8_t)pkb;
    }
  }
}

// ---------------------------------------------------------------------------
// GEMM2 (i8, packed-B): M=512, K=2048 (BK=128, 16 K-tiles), LDS 40KB
// (A 16K + packed B 8K; 40K for epilogue reuse). Shallow 2-barrier loop.
// Fused dequant+BN2 + residual + LDS-transpose float4 stores. XCD swizzle.
__launch_bounds__(512)
__global__ void gemm2_out_kernel(const signed char* __restrict__ W2q,
                                 const signed char* __restrict__ s2,
                                 const float* __restrict__ scale2,
                                 const float* __restrict__ bias2,
                                 const float* __restrict__ xin,
                                 float* __restrict__ outp) {
  __shared__ __align__(16) char lds[40960];
  char* ldsA = lds;               // 16KB
  char* ldsB = lds + 16384;       // 8KB packed
  float* ep = (float*)lds;        // epilogue reuse (40KB)
  const uint32_t tid = threadIdx.x;
  const uint32_t wid = tid >> 6;
  const uint32_t lane = tid & 63u;
  const uint32_t il = lane & 15u, g = lane >> 4;
  const uint32_t wm = wid >> 2, wn = wid & 3u;
  const uint32_t bid = blockIdx.x;
  const uint32_t lid = (bid & 7u) * 49u + (bid >> 3);
  const uint32_t m0 = (lid & 3u) * 128u;
  const uint32_t n0 = (lid >> 2) * 64u;

  i32x4 acc[4][4];
  #pragma unroll
  for (int i = 0; i < 4; ++i)
    #pragma unroll
    for (int j = 0; j < 4; ++j) acc[i][j] = (i32x4){0, 0, 0, 0};

  for (int kt = 0; kt < 16; ++kt) {
    {                                      // packed B tile: 512 chunks
      uint32_t cb = tid >> 8, rem = tid & 255u;
      uint32_t tt = rem >> 6, dn = rem & 63u;
      const char* src = (const char*)s2
          + (size_t)((((uint32_t)kt * 2u + cb) * 4u + tt) * NCOL + n0 + dn) * 16u;
      async16(src, ldsB + (size_t)tid * 16u);
    }
    #pragma unroll
    for (uint32_t r = 0; r < 2; ++r) {     // A tile (L2): 1024 chunks
      uint32_t cid = r * 512u + tid;
      uint32_t i = cid >> 3, q = cid & 7u;
      const char* src = (const char*)W2q + (size_t)(m0 + i) * 2048u
                        + (size_t)((uint32_t)kt * 128u) + (size_t)((q ^ (i & 7u)) * 16u);
      async16(src, ldsA + (size_t)cid * 16u);
    }
    __syncthreads();
    #pragma unroll
    for (int ks = 0; ks < 2; ++ks) {
      i32x4 af[4], bfr0, bfr1;
      #pragma unroll
      for (int fm = 0; fm < 4; ++fm) {
        uint32_t i = wm * 64u + (uint32_t)fm * 16u + il;
        uint32_t q = (uint32_t)ks * 4u + g;
        af[fm] = *(const i32x4*)(ldsA + (i * 8u + (q ^ (i & 7u))) * 16u);
      }
      #pragma unroll
      for (int th = 0; th < 2; ++th) {
        uint32_t pb = (((uint32_t)ks * 4u + (uint32_t)th * 2u) * 64u
                       + wn * 16u + il) * 16u + g * 4u;
        uint32_t b0 = *(const uint32_t*)(ldsB + pb);
        uint32_t b1 = *(const uint32_t*)(ldsB + pb + 1024u);
        bfr0 = expand16(b0);
        bfr1 = expand16(b1);
        #pragma unroll
        for (int fm = 0; fm < 4; ++fm) {
          acc[fm][th*2]   = MFMA_I8(af[fm], bfr0, acc[fm][th*2], 0, 0, 0);
          acc[fm][th*2+1] = MFMA_I8(af[fm], bfr1, acc[fm][th*2+1], 0, 0, 0);
        }
      }
    }
    __syncthreads();
  }

  // epilogue: dequant+BN2 (folded) + residual, LDS transpose -> float4 stores
  const uint32_t cl = lane >> 2, qq = lane & 3u;
  #pragma unroll
  for (int fm = 0; fm < 4; ++fm) {
    const uint32_t cbase = m0 + wm * 64u + (uint32_t)fm * 16u;
    f32x4 sc = *(const f32x4*)&scale2[cbase + 4u * g];
    f32x4 bi = *(const f32x4*)&bias2[cbase + 4u * g];
    #pragma unroll
    for (int t = 0; t < 4; ++t)
      #pragma unroll
      for (int r = 0; r < 4; ++r)
        ep[wid * 1280u + ((4u * g + (uint32_t)r) * 4u + (uint32_t)t) * 20u + il]
            = (float)acc[fm][t][r] * sc[r] + bi[r];
    __syncthreads();
    #pragma unroll
    for (int t = 0; t < 4; ++t) {
      f32x4 val = *(const f32x4*)&ep[wid * 1280u + (cl * 4u + (uint32_t)t) * 20u + qq * 4u];
      uint32_t nn = n0 + wn * 16u + qq * 4u;
      uint32_t b = nn / 196u, hw = nn - b * 196u;
      uint32_t c = cbase + cl;
      size_t off = (((size_t)t * 32u + b) * 512u + c) * 196u + hw;
      f32x4 iv = *(const f32x4*)(xin + off);
      *(f32x4*)(outp + off) = val + iv;
    }
    __syncthreads();
  }
}

// ---------------------------------------------------------------------------
extern "C" void kernel_launch(void* const* d_in, const int* in_sizes, int n_in,
                              void* d_out, int out_size, void* d_ws, size_t ws_size,
                              hipStream_t stream) {
  const float* x  = (const float*)d_in[0];
  const float* W1 = (const float*)d_in[1];
  const float* g1 = (const float*)d_in[2];
  const float* b1 = (const float*)d_in[3];
  const float* m1 = (const float*)d_in[4];
  const float* v1 = (const float*)d_in[5];
  const float* W2 = (const float*)d_in[6];
  const float* g2 = (const float*)d_in[7];
  const float* b2 = (const float*)d_in[8];
  const float* m2 = (const float*)d_in[9];
  const float* v2 = (const float*)d_in[10];
  float* out = (float*)d_out;
  char* ws = (char*)d_ws;

  signed char* s2b    = (signed char*)(ws);               // 12,845,056 B packed [32cb][4t][6272][16B]
  signed char* s1b    = (signed char*)(ws + 16777216);    //  3,211,264 B packed [8cb][4t][6272][16B]
  signed char* W1q    = (signed char*)(ws + 20971520);    //  1,048,576 B [2048][512] i8
  signed char* W2q    = (signed char*)(ws + 22020096);    //  1,048,576 B [512][2048] i8
  float*       scale1 = (float*)(ws + 23068672);
  float*       bias1  = (float*)(ws + 23076864);
  float*       scale2 = (float*)(ws + 23085056);
  float*       bias2  = (float*)(ws + 23087104);

  prep1_kernel<<<2048, 256, 0, stream>>>(W1, g1, b1, m1, v1, W1q, scale1, bias1);
  prep2_kernel<<<512, 256, 0, stream>>>(W2, g2, b2, m2, v2, W2q, scale2, bias2);
  lif1_kernel<<<dim3(8, 98), 256, 0, stream>>>(x, s1b);
  gemm1_lif2_kernel<<<1568, 512, 0, stream>>>(W1q, s1b, scale1, bias1, s2b);
  gemm2_out_kernel<<<392, 512, 0, stream>>>(W2q, s2b, scale2, bias2, x, out);
}